// Round 1
// baseline (671.473 us; speedup 1.0000x reference)
//
#include <hip/hip_runtime.h>
#include <stdint.h>
#include <stddef.h>

#define DIM 1024
#define HEADS 16
#define HDIM 64
#define NTOK 2048

typedef __attribute__((ext_vector_type(8))) __bf16 bf16x8;
typedef __attribute__((ext_vector_type(4))) float f32x4;
typedef __attribute__((ext_vector_type(4))) short short4v;

__device__ __forceinline__ short f2bs(float f) {
  // round-to-nearest-even f32 -> bf16 (inputs are never NaN here)
  uint32_t u = __builtin_bit_cast(uint32_t, f);
  uint32_t r = (u + 0x7FFFu + ((u >> 16) & 1u)) >> 16;
  return (short)r;
}

__device__ __forceinline__ f32x4 MFMA(bf16x8 a, bf16x8 b, f32x4 c) {
  return __builtin_amdgcn_mfma_f32_16x16x32_bf16(a, b, c, 0, 0, 0);
}

__device__ __forceinline__ void gl_lds16(const void* g, void* l) {
  __builtin_amdgcn_global_load_lds(
      (const __attribute__((address_space(1))) void*)g,
      (__attribute__((address_space(3))) void*)l, 16, 0, 0);
}

// ---------------- cast embeddings (f32 -> bf16 rows of X) ----------------
__global__ __launch_bounds__(256) void cast_embs(const float4* __restrict__ e1,
                                                 const float4* __restrict__ e2,
                                                 short* __restrict__ X) {
  int i = blockIdx.x * 256 + threadIdx.x;      // 0 .. 2097151, 4 floats each
  const int half4 = (4096 * 1024) / 4;         // 1048576
  float4 v = (i < half4) ? e1[i] : e2[i - half4];
  short4v o;
  o.x = f2bs(v.x); o.y = f2bs(v.y); o.z = f2bs(v.z); o.w = f2bs(v.w);
  *(short4v*)&X[(size_t)i * 4] = o;
}

// ---------------- transpose + cast weights: W[R][C] f32 -> Wt[C][R] bf16 --
__global__ __launch_bounds__(256) void transpose_cast(const float* __restrict__ W,
                                                      short* __restrict__ Wt,
                                                      int R, int C) {
  __shared__ float tile[32][33];
  int tx = threadIdx.x, ty = threadIdx.y;      // 32 x 8
  int c0 = blockIdx.x * 32, r0 = blockIdx.y * 32;
#pragma unroll
  for (int i = 0; i < 32; i += 8)
    tile[ty + i][tx] = W[(size_t)(r0 + ty + i) * C + c0 + tx];
  __syncthreads();
#pragma unroll
  for (int i = 0; i < 32; i += 8)
    Wt[(size_t)(c0 + ty + i) * R + r0 + tx] = f2bs(tile[tx][ty + i]);
}

// ---------------- MFMA GEMM, C = A[M,K] * Bt[N,K]^T ----------------------
// EPI 0: QKV epilogue (bias + scatter to q/k/vt bf16 buffers)
// EPI 1: out-proj epilogue (bias + residual(f32 emb) -> f32 Y)
template <int EPI>
__global__ __launch_bounds__(256, 2) void gemm_bt(
    const short* __restrict__ A, const short* __restrict__ Bt, int K,
    const float* __restrict__ bias,
    const float* __restrict__ e1, const float* __restrict__ e2,
    short* __restrict__ oq, short* __restrict__ okk, short* __restrict__ ovt,
    float* __restrict__ oy) {
  __shared__ short lA[128 * 32];
  __shared__ short lB[128 * 32];
  int tid = threadIdx.x;
  int l = tid & 63, w = tid >> 6;
  int wr = w >> 1, wc = w & 1;
  int row0 = blockIdx.x * 128, col0 = blockIdx.y * 128;
  f32x4 acc[4][4] = {};

  for (int kk = 0; kk < K; kk += 32) {
#pragma unroll
    for (int i = 0; i < 2; i++) {
      int f = i * 256 + tid;            // 0..511 16-byte chunks
      int r = f >> 2, cb = (f & 3) * 8; // row, col-elem base
      gl_lds16(A + (size_t)(row0 + r) * K + kk + cb, (char*)lA + (size_t)f * 16);
      gl_lds16(Bt + (size_t)(col0 + r) * K + kk + cb, (char*)lB + (size_t)f * 16);
    }
    __syncthreads();
    bf16x8 af[4], bfr[4];
#pragma unroll
    for (int mi = 0; mi < 4; mi++)
      af[mi] = *(const bf16x8*)&lA[(wr * 64 + mi * 16 + (l & 15)) * 32 + (l >> 4) * 8];
#pragma unroll
    for (int ni = 0; ni < 4; ni++)
      bfr[ni] = *(const bf16x8*)&lB[(wc * 64 + ni * 16 + (l & 15)) * 32 + (l >> 4) * 8];
#pragma unroll
    for (int mi = 0; mi < 4; mi++)
#pragma unroll
      for (int ni = 0; ni < 4; ni++)
        acc[mi][ni] = MFMA(af[mi], bfr[ni], acc[mi][ni]);
    __syncthreads();
  }

#pragma unroll
  for (int mi = 0; mi < 4; mi++) {
#pragma unroll
    for (int ni = 0; ni < 4; ni++) {
#pragma unroll
      for (int r = 0; r < 4; r++) {
        int grow = row0 + wr * 64 + mi * 16 + (l >> 4) * 4 + r;
        int gcol = col0 + wc * 64 + ni * 16 + (l & 15);
        float v = acc[mi][ni][r] + bias[gcol];
        if (EPI == 0) {
          int t = gcol >> 10, rem = gcol & 1023;
          int h = rem >> 6, d = rem & 63;
          int e = grow >> 12, b = (grow >> 11) & 1, n = grow & 2047;
          size_t ebh = (size_t)((e * 2 + b) * 16 + h) * NTOK * HDIM;
          short sv = f2bs(v);
          if (t == 0)      oq[ebh + (size_t)n * HDIM + d] = sv;
          else if (t == 1) okk[ebh + (size_t)n * HDIM + d] = sv;
          else             ovt[ebh + (size_t)d * NTOK + n] = sv;
        } else {
          float res = (grow < 4096) ? e1[(size_t)grow * DIM + gcol]
                                    : e2[(size_t)(grow - 4096) * DIM + gcol];
          oy[(size_t)grow * DIM + gcol] = v + res;
        }
      }
    }
  }
}

// ---------------- fused cross-attention (flash-style) --------------------
// grid: (a,b,h,qb): a selects (q from emb a, k/v from emb a^1)
__global__ __launch_bounds__(256, 4) void attn_kernel(
    const short* __restrict__ qbuf, const short* __restrict__ kbuf,
    const short* __restrict__ vtbuf, short* __restrict__ X2) {
  int idx = blockIdx.x;
  int qb = idx & 31, h = (idx >> 5) & 15, b = (idx >> 9) & 1, a = (idx >> 10) & 1;
  int tid = threadIdx.x, w = tid >> 6, l = tid & 63;
  size_t qo = (size_t)((a * 2 + b) * 16 + h) * NTOK * HDIM;
  size_t ko = (size_t)(((a ^ 1) * 2 + b) * 16 + h) * NTOK * HDIM;
  const short* Q = qbuf + qo;
  const short* Kp = kbuf + ko;
  const short* Vt = vtbuf + ko;
  int qrow0 = qb * 64 + w * 16;

  bf16x8 aq0 = *(const bf16x8*)&Q[(size_t)(qrow0 + (l & 15)) * HDIM + (l >> 4) * 8];
  bf16x8 aq1 = *(const bf16x8*)&Q[(size_t)(qrow0 + (l & 15)) * HDIM + 32 + (l >> 4) * 8];

  const float sc = 0.125f * 1.44269504088896f;  // scale * log2(e)
  float m0[4], ls[4];
  f32x4 o[4] = {};
#pragma unroll
  for (int r = 0; r < 4; r++) { m0[r] = -1e30f; ls[r] = 0.f; }

  __shared__ short plds[4][16 * 40];
  short* pw = &plds[w][0];

  for (int s0 = 0; s0 < NTOK; s0 += 32) {
    f32x4 st0 = {}, st1 = {};
    {
      const short* k0 = &Kp[(size_t)(s0 + (l & 15)) * HDIM + (l >> 4) * 8];
      const short* k1 = &Kp[(size_t)(s0 + 16 + (l & 15)) * HDIM + (l >> 4) * 8];
      st0 = MFMA(aq0, *(const bf16x8*)k0, st0);
      st0 = MFMA(aq1, *(const bf16x8*)(k0 + 32), st0);
      st1 = MFMA(aq0, *(const bf16x8*)k1, st1);
      st1 = MFMA(aq1, *(const bf16x8*)(k1 + 32), st1);
    }
    float p0[4], p1[4], pm[4];
#pragma unroll
    for (int r = 0; r < 4; r++) {
      p0[r] = st0[r] * sc; p1[r] = st1[r] * sc;
      pm[r] = fmaxf(p0[r], p1[r]);
    }
#pragma unroll
    for (int d = 1; d < 16; d <<= 1)
#pragma unroll
      for (int r = 0; r < 4; r++) pm[r] = fmaxf(pm[r], __shfl_xor(pm[r], d));
    float scl[4], rs[4];
#pragma unroll
    for (int r = 0; r < 4; r++) {
      float mn = fmaxf(m0[r], pm[r]);
      scl[r] = exp2f(m0[r] - mn);
      m0[r] = mn;
      p0[r] = exp2f(p0[r] - mn);
      p1[r] = exp2f(p1[r] - mn);
      rs[r] = p0[r] + p1[r];
    }
#pragma unroll
    for (int d = 1; d < 16; d <<= 1)
#pragma unroll
      for (int r = 0; r < 4; r++) rs[r] += __shfl_xor(rs[r], d);
#pragma unroll
    for (int r = 0; r < 4; r++) {
      ls[r] = ls[r] * scl[r] + rs[r];
      o[0][r] *= scl[r]; o[1][r] *= scl[r]; o[2][r] *= scl[r]; o[3][r] *= scl[r];
    }
    // store P tile (16 rows x 32 keys) bf16, padded stride 40 (2-way free)
#pragma unroll
    for (int r = 0; r < 4; r++) {
      int prow = (l >> 4) * 4 + r;
      pw[prow * 40 + (l & 15)] = f2bs(p0[r]);
      pw[prow * 40 + 16 + (l & 15)] = f2bs(p1[r]);
    }
    bf16x8 ap = *(const bf16x8*)&pw[(l & 15) * 40 + (l >> 4) * 8];
#pragma unroll
    for (int dg = 0; dg < 4; dg++) {
      bf16x8 bv = *(const bf16x8*)&Vt[(size_t)(dg * 16 + (l & 15)) * NTOK + s0 + (l >> 4) * 8];
      o[dg] = MFMA(ap, bv, o[dg]);
    }
  }
  // epilogue: write attn output row-major [token][DIM] bf16
#pragma unroll
  for (int dg = 0; dg < 4; dg++)
#pragma unroll
    for (int r = 0; r < 4; r++) {
      int n = qrow0 + (l >> 4) * 4 + r;
      int col = h * HDIM + dg * 16 + (l & 15);
      float v = o[dg][r] / ls[r];
      X2[(size_t)(a * 4096 + b * 2048 + n) * DIM + col] = f2bs(v);
    }
}

// ---------------- LayerNorm over rows of Y (f32) -------------------------
__global__ __launch_bounds__(256) void ln_kernel(const float* __restrict__ Y,
                                                 const float* __restrict__ gamma,
                                                 const float* __restrict__ beta,
                                                 float* __restrict__ out) {
  int row = blockIdx.x, t = threadIdx.x;
  const float4 v = *(const float4*)&Y[(size_t)row * DIM + t * 4];
  float s = v.x + v.y + v.z + v.w;
  float s2 = v.x * v.x + v.y * v.y + v.z * v.z + v.w * v.w;
#pragma unroll
  for (int d = 1; d < 64; d <<= 1) { s += __shfl_xor(s, d); s2 += __shfl_xor(s2, d); }
  __shared__ float sb[8];
  int w = t >> 6, l = t & 63;
  if (l == 0) { sb[w] = s; sb[4 + w] = s2; }
  __syncthreads();
  s = sb[0] + sb[1] + sb[2] + sb[3];
  s2 = sb[4] + sb[5] + sb[6] + sb[7];
  float mu = s * (1.f / DIM);
  float var = s2 * (1.f / DIM) - mu * mu;
  float rr = rsqrtf(var + 1e-5f);
  const float4 g = *(const float4*)&gamma[t * 4];
  const float4 bb = *(const float4*)&beta[t * 4];
  float4 ov;
  ov.x = (v.x - mu) * rr * g.x + bb.x;
  ov.y = (v.y - mu) * rr * g.y + bb.y;
  ov.z = (v.z - mu) * rr * g.z + bb.z;
  ov.w = (v.w - mu) * rr * g.w + bb.w;
  *(float4*)&out[(size_t)row * DIM + t * 4] = ov;
}

extern "C" void kernel_launch(void* const* d_in, const int* in_sizes, int n_in,
                              void* d_out, int out_size, void* d_ws, size_t ws_size,
                              hipStream_t stream) {
  const float* e1 = (const float*)d_in[0];
  const float* e2 = (const float*)d_in[1];
  const float* Wqkv = (const float*)d_in[2];
  const float* bqkv = (const float*)d_in[3];
  const float* Wout = (const float*)d_in[4];
  const float* bout = (const float*)d_in[5];
  const float* gamma = (const float*)d_in[6];
  const float* beta = (const float*)d_in[7];

  char* p = (char*)d_ws;
  short* Xbf   = (short*)p;                     // 16,777,216 B (also X2 later)
  short* Wqkvt = (short*)(p + 16777216);        //  6,291,456 B
  short* Woutt = (short*)(p + 23068672);        //  2,097,152 B
  short* qbf   = (short*)(p + 25165824);        // 16,777,216 B
  short* kbf   = (short*)(p + 41943040);        // 16,777,216 B
  short* vtf   = (short*)(p + 58720256);        // 16,777,216 B (end 75,497,472)
  float* Yres  = (float*)(p + 25165824);        // aliases qbf+kbf (33,554,432 B)
  short* X2    = Xbf;                           // aliases Xbf (dead after QKV gemm)
  float* out   = (float*)d_out;

  cast_embs<<<8192, 256, 0, stream>>>((const float4*)e1, (const float4*)e2, Xbf);
  transpose_cast<<<dim3(3072 / 32, 1024 / 32), dim3(32, 8), 0, stream>>>(Wqkv, Wqkvt, 1024, 3072);
  transpose_cast<<<dim3(1024 / 32, 1024 / 32), dim3(32, 8), 0, stream>>>(Wout, Woutt, 1024, 1024);
  gemm_bt<0><<<dim3(64, 24), 256, 0, stream>>>(Xbf, Wqkvt, 1024, bqkv,
                                               nullptr, nullptr, qbf, kbf, vtf, nullptr);
  attn_kernel<<<2048, 256, 0, stream>>>(qbf, kbf, vtf, X2);
  gemm_bt<1><<<dim3(64, 8), 256, 0, stream>>>(X2, Woutt, 1024, bout,
                                              e1, e2, nullptr, nullptr, nullptr, Yres);
  ln_kernel<<<8192, 256, 0, stream>>>(Yres, gamma, beta, out);
}

// Round 2
// 510.457 us; speedup vs baseline: 1.3154x; 1.3154x over previous
//
#include <hip/hip_runtime.h>
#include <stdint.h>
#include <stddef.h>

#define DIM 1024
#define HEADS 16
#define HDIM 64
#define NTOK 2048

typedef __attribute__((ext_vector_type(8))) __bf16 bf16x8;
typedef __attribute__((ext_vector_type(4))) float f32x4;
typedef __attribute__((ext_vector_type(16))) float f32x16;
typedef __attribute__((ext_vector_type(4))) short short4v;
typedef __attribute__((ext_vector_type(4))) uint32_t u32x4;

__device__ __forceinline__ short f2bs(float f) {
  // round-to-nearest-even f32 -> bf16
  uint32_t u = __builtin_bit_cast(uint32_t, f);
  uint32_t r = (u + 0x7FFFu + ((u >> 16) & 1u)) >> 16;
  return (short)r;
}

__device__ __forceinline__ uint32_t cvtpk(float lo, float hi) {
  uint32_t r;
  asm("v_cvt_pk_bf16_f32 %0, %1, %2" : "=v"(r) : "v"(lo), "v"(hi));
  return r;
}

__device__ __forceinline__ f32x4 MFMA(bf16x8 a, bf16x8 b, f32x4 c) {
  return __builtin_amdgcn_mfma_f32_16x16x32_bf16(a, b, c, 0, 0, 0);
}
__device__ __forceinline__ f32x16 MFMA32(bf16x8 a, bf16x8 b, f32x16 c) {
  return __builtin_amdgcn_mfma_f32_32x32x16_bf16(a, b, c, 0, 0, 0);
}

__device__ __forceinline__ void gl_lds16(const void* g, void* l) {
  __builtin_amdgcn_global_load_lds(
      (const __attribute__((address_space(1))) void*)g,
      (__attribute__((address_space(3))) void*)l, 16, 0, 0);
}

// ---------------- cast embeddings (f32 -> bf16 rows of X) ----------------
__global__ __launch_bounds__(256) void cast_embs(const float4* __restrict__ e1,
                                                 const float4* __restrict__ e2,
                                                 short* __restrict__ X) {
  int i = blockIdx.x * 256 + threadIdx.x;
  const int half4 = (4096 * 1024) / 4;
  float4 v = (i < half4) ? e1[i] : e2[i - half4];
  short4v o;
  o.x = f2bs(v.x); o.y = f2bs(v.y); o.z = f2bs(v.z); o.w = f2bs(v.w);
  *(short4v*)&X[(size_t)i * 4] = o;
}

// ---------------- transpose + cast weights: W[R][C] f32 -> Wt[C][R] bf16 --
__global__ __launch_bounds__(256) void transpose_cast(const float* __restrict__ W,
                                                      short* __restrict__ Wt,
                                                      int R, int C) {
  __shared__ float tile[32][33];
  int tx = threadIdx.x, ty = threadIdx.y;      // 32 x 8
  int c0 = blockIdx.x * 32, r0 = blockIdx.y * 32;
#pragma unroll
  for (int i = 0; i < 32; i += 8)
    tile[ty + i][tx] = W[(size_t)(r0 + ty + i) * C + c0 + tx];
  __syncthreads();
#pragma unroll
  for (int i = 0; i < 32; i += 8)
    Wt[(size_t)(c0 + ty + i) * R + r0 + tx] = f2bs(tile[tx][ty + i]);
}

// ---------------- MFMA GEMM, C = A[M,K] * Bt[N,K]^T ----------------------
template <int EPI>
__global__ __launch_bounds__(256, 2) void gemm_bt(
    const short* __restrict__ A, const short* __restrict__ Bt, int K,
    const float* __restrict__ bias,
    const float* __restrict__ e1, const float* __restrict__ e2,
    short* __restrict__ oq, short* __restrict__ okk, short* __restrict__ ovt,
    float* __restrict__ oy) {
  __shared__ short lA[128 * 32];
  __shared__ short lB[128 * 32];
  int tid = threadIdx.x;
  int l = tid & 63, w = tid >> 6;
  int wr = w >> 1, wc = w & 1;
  int row0 = blockIdx.x * 128, col0 = blockIdx.y * 128;
  f32x4 acc[4][4] = {};

  for (int kk = 0; kk < K; kk += 32) {
#pragma unroll
    for (int i = 0; i < 2; i++) {
      int f = i * 256 + tid;
      int r = f >> 2, cb = (f & 3) * 8;
      gl_lds16(A + (size_t)(row0 + r) * K + kk + cb, (char*)lA + (size_t)f * 16);
      gl_lds16(Bt + (size_t)(col0 + r) * K + kk + cb, (char*)lB + (size_t)f * 16);
    }
    __syncthreads();
    bf16x8 af[4], bfr[4];
#pragma unroll
    for (int mi = 0; mi < 4; mi++)
      af[mi] = *(const bf16x8*)&lA[(wr * 64 + mi * 16 + (l & 15)) * 32 + (l >> 4) * 8];
#pragma unroll
    for (int ni = 0; ni < 4; ni++)
      bfr[ni] = *(const bf16x8*)&lB[(wc * 64 + ni * 16 + (l & 15)) * 32 + (l >> 4) * 8];
#pragma unroll
    for (int mi = 0; mi < 4; mi++)
#pragma unroll
      for (int ni = 0; ni < 4; ni++)
        acc[mi][ni] = MFMA(af[mi], bfr[ni], acc[mi][ni]);
    __syncthreads();
  }

#pragma unroll
  for (int mi = 0; mi < 4; mi++) {
#pragma unroll
    for (int ni = 0; ni < 4; ni++) {
#pragma unroll
      for (int r = 0; r < 4; r++) {
        int grow = row0 + wr * 64 + mi * 16 + (l >> 4) * 4 + r;
        int gcol = col0 + wc * 64 + ni * 16 + (l & 15);
        float v = acc[mi][ni][r] + bias[gcol];
        if (EPI == 0) {
          int t = gcol >> 10, rem = gcol & 1023;
          int h = rem >> 6, d = rem & 63;
          int e = grow >> 12, b = (grow >> 11) & 1, n = grow & 2047;
          size_t ebh = (size_t)((e * 2 + b) * 16 + h) * NTOK * HDIM;
          if (t == 0) {
            // fold softmax scale * log2(e) into Q
            oq[ebh + (size_t)n * HDIM + d] = f2bs(v * 0.18033688f);
          } else if (t == 1) {
            okk[ebh + (size_t)n * HDIM + d] = f2bs(v);
          } else {
            ovt[ebh + (size_t)d * NTOK + n] = f2bs(v);
          }
        } else {
          float res = (grow < 4096) ? e1[(size_t)grow * DIM + gcol]
                                    : e2[(size_t)(grow - 4096) * DIM + gcol];
          oy[(size_t)grow * DIM + gcol] = v + res;
        }
      }
    }
  }
}

// ---------------- fused cross-attention, swapped-QK^T in-register softmax --
// 4 waves/block, QBLK=32 rows/wave, KVBLK=64. No LDS. O^T accumulation.
__global__ __launch_bounds__(256) void attn_kernel(
    const short* __restrict__ qbuf, const short* __restrict__ kbuf,
    const short* __restrict__ vtbuf, short* __restrict__ X2) {
  // bijective XCD swizzle: each instance's 16 blocks land on one XCD
  int phys = blockIdx.x;
  int work = (phys & 7) * 128 + (phys >> 3);   // grid 1024 = 8*128
  int qb = work & 15;                          // 16 q-blocks of 128 rows
  int inst = work >> 4;                        // 0..63
  int h = inst & 15, b = (inst >> 4) & 1, a = inst >> 5;
  int tid = threadIdx.x, w = tid >> 6, l = tid & 63;
  int lo5 = l & 31, hi = l >> 5;

  size_t qo = (size_t)((a * 2 + b) * 16 + h) * NTOK * HDIM;
  size_t ko = (size_t)(((a ^ 1) * 2 + b) * 16 + h) * NTOK * HDIM;
  const short* Q = qbuf + qo;
  const short* Kp = kbuf + ko;
  const short* Vt = vtbuf + ko;
  int qrow = qb * 128 + w * 32 + lo5;          // this lane's q row (= MFMA col)

  // Q B-fragments: B[col=q][k = hi*8 + 16*ks + j]  (Q pre-scaled by sc*log2e)
  bf16x8 qf[4];
#pragma unroll
  for (int ks = 0; ks < 4; ks++)
    qf[ks] = *(const bf16x8*)&Q[(size_t)qrow * HDIM + hi * 8 + ks * 16];

  f32x16 o0 = {}, o1 = {};
  float m = -1e30f, lsum = 0.f;

  for (int s0 = 0; s0 < NTOK; s0 += 64) {
    // ---- QK^T (swapped): st[t][reg] = S^T[kv = kvt(reg)+32t][q = lo5]
    f32x16 st0 = {}, st1 = {};
#pragma unroll
    for (int ks = 0; ks < 4; ks++) {
      bf16x8 k0 = *(const bf16x8*)&Kp[(size_t)(s0 + lo5) * HDIM + hi * 8 + ks * 16];
      bf16x8 k1 = *(const bf16x8*)&Kp[(size_t)(s0 + 32 + lo5) * HDIM + hi * 8 + ks * 16];
      st0 = MFMA32(k0, qf[ks], st0);
      st1 = MFMA32(k1, qf[ks], st1);
    }
    // ---- row max over this lane's 32 scores + partner half
    float pm = fmaxf(st0[0], st1[0]);
#pragma unroll
    for (int i = 1; i < 16; i++) pm = fmaxf(pm, fmaxf(st0[i], st1[i]));
    pm = fmaxf(pm, __shfl_xor(pm, 32));
    // ---- defer-max rescale (THR = 8 in log2 domain)
    if (!__all(pm <= m + 8.f)) {
      float mn = fmaxf(m, pm);
      float scl = exp2f(m - mn);
      lsum *= scl;
      o0 *= scl;
      o1 *= scl;
      m = mn;
    }
    // ---- P = exp2(S - m), row sum
    f32x16 pv0, pv1;
    float rs = 0.f;
#pragma unroll
    for (int i = 0; i < 16; i++) { pv0[i] = exp2f(st0[i] - m); rs += pv0[i]; }
#pragma unroll
    for (int i = 0; i < 16; i++) { pv1[i] = exp2f(st1[i] - m); rs += pv1[i]; }
    rs += __shfl_xor(rs, 32);
    lsum += rs;
    // ---- pack P into PV B-fragments: B[col=q][k = kv = 16ks + hi*8 + j]
    bf16x8 pf[4];
#pragma unroll
    for (int ks = 0; ks < 4; ks++) {
      f32x16 pt = (ks < 2) ? pv0 : pv1;
      const int rb = (ks & 1) * 8;
      uint32_t w0 = cvtpk(pt[rb + 0], pt[rb + 1]);   // kv16 {0,1}+4hi
      uint32_t w1 = cvtpk(pt[rb + 2], pt[rb + 3]);   // kv16 {2,3}+4hi
      uint32_t w2 = cvtpk(pt[rb + 4], pt[rb + 5]);   // kv16 {8,9}+4hi
      uint32_t w3 = cvtpk(pt[rb + 6], pt[rb + 7]);   // kv16 {10,11}+4hi
      uint32_t x0 = __shfl_xor(w0, 32);
      uint32_t x1 = __shfl_xor(w1, 32);
      uint32_t x2 = __shfl_xor(w2, 32);
      uint32_t x3 = __shfl_xor(w3, 32);
      u32x4 fw;
      fw.x = hi ? x2 : w0;   // kv16 0,1 | 8,9
      fw.y = hi ? x3 : w1;   // kv16 2,3 | 10,11
      fw.z = hi ? w2 : x0;   // kv16 4,5 | 12,13
      fw.w = hi ? w3 : x1;   // kv16 6,7 | 14,15
      pf[ks] = __builtin_bit_cast(bf16x8, fw);
    }
    // ---- PV (O^T): o[T] += Vt-tile^T-frag x P-frag ; C[row=d][col=q]
#pragma unroll
    for (int ks = 0; ks < 4; ks++) {
      bf16x8 v0 = *(const bf16x8*)&Vt[(size_t)lo5 * NTOK + s0 + hi * 8 + ks * 16];
      bf16x8 v1 = *(const bf16x8*)&Vt[(size_t)(32 + lo5) * NTOK + s0 + hi * 8 + ks * 16];
      o0 = MFMA32(v0, pf[ks], o0);
      o1 = MFMA32(v1, pf[ks], o1);
    }
    __syncthreads();   // keep block's waves on the same K/V tile (L1 reuse)
  }

  // ---- epilogue: X2[token][h*64 + d] = O[q][d] / lsum, bf16
  float inv = 1.f / lsum;
  size_t obase = (size_t)(a * 4096 + b * 2048 + qrow) * DIM + h * HDIM;
#pragma unroll
  for (int g = 0; g < 4; g++) {
    // regs 4g..4g+3 are d = 8g + 4hi + {0,1,2,3}
    short4v s4;
    s4.x = f2bs(o0[4 * g + 0] * inv);
    s4.y = f2bs(o0[4 * g + 1] * inv);
    s4.z = f2bs(o0[4 * g + 2] * inv);
    s4.w = f2bs(o0[4 * g + 3] * inv);
    *(short4v*)&X2[obase + 8 * g + 4 * hi] = s4;
    short4v s5;
    s5.x = f2bs(o1[4 * g + 0] * inv);
    s5.y = f2bs(o1[4 * g + 1] * inv);
    s5.z = f2bs(o1[4 * g + 2] * inv);
    s5.w = f2bs(o1[4 * g + 3] * inv);
    *(short4v*)&X2[obase + 32 + 8 * g + 4 * hi] = s5;
  }
}

// ---------------- LayerNorm over rows of Y (f32) -------------------------
__global__ __launch_bounds__(256) void ln_kernel(const float* __restrict__ Y,
                                                 const float* __restrict__ gamma,
                                                 const float* __restrict__ beta,
                                                 float* __restrict__ out) {
  int row = blockIdx.x, t = threadIdx.x;
  const float4 v = *(const float4*)&Y[(size_t)row * DIM + t * 4];
  float s = v.x + v.y + v.z + v.w;
  float s2 = v.x * v.x + v.y * v.y + v.z * v.z + v.w * v.w;
#pragma unroll
  for (int d = 1; d < 64; d <<= 1) { s += __shfl_xor(s, d); s2 += __shfl_xor(s2, d); }
  __shared__ float sb[8];
  int w = t >> 6, l = t & 63;
  if (l == 0) { sb[w] = s; sb[4 + w] = s2; }
  __syncthreads();
  s = sb[0] + sb[1] + sb[2] + sb[3];
  s2 = sb[4] + sb[5] + sb[6] + sb[7];
  float mu = s * (1.f / DIM);
  float var = s2 * (1.f / DIM) - mu * mu;
  float rr = rsqrtf(var + 1e-5f);
  const float4 g = *(const float4*)&gamma[t * 4];
  const float4 bb = *(const float4*)&beta[t * 4];
  float4 ov;
  ov.x = (v.x - mu) * rr * g.x + bb.x;
  ov.y = (v.y - mu) * rr * g.y + bb.y;
  ov.z = (v.z - mu) * rr * g.z + bb.z;
  ov.w = (v.w - mu) * rr * g.w + bb.w;
  *(float4*)&out[(size_t)row * DIM + t * 4] = ov;
}

extern "C" void kernel_launch(void* const* d_in, const int* in_sizes, int n_in,
                              void* d_out, int out_size, void* d_ws, size_t ws_size,
                              hipStream_t stream) {
  const float* e1 = (const float*)d_in[0];
  const float* e2 = (const float*)d_in[1];
  const float* Wqkv = (const float*)d_in[2];
  const float* bqkv = (const float*)d_in[3];
  const float* Wout = (const float*)d_in[4];
  const float* bout = (const float*)d_in[5];
  const float* gamma = (const float*)d_in[6];
  const float* beta = (const float*)d_in[7];

  char* p = (char*)d_ws;
  short* Xbf   = (short*)p;                     // 16 MiB (also X2 later)
  short* Wqkvt = (short*)(p + 16777216);        //  6 MiB
  short* Woutt = (short*)(p + 23068672);        //  2 MiB
  short* qbf   = (short*)(p + 25165824);        // 16 MiB
  short* kbf   = (short*)(p + 41943040);        // 16 MiB
  short* vtf   = (short*)(p + 58720256);        // 16 MiB
  float* Yres  = (float*)(p + 25165824);        // aliases qbf+kbf
  short* X2    = Xbf;
  float* out   = (float*)d_out;

  cast_embs<<<8192, 256, 0, stream>>>((const float4*)e1, (const float4*)e2, Xbf);
  transpose_cast<<<dim3(3072 / 32, 1024 / 32), dim3(32, 8), 0, stream>>>(Wqkv, Wqkvt, 1024, 3072);
  transpose_cast<<<dim3(1024 / 32, 1024 / 32), dim3(32, 8), 0, stream>>>(Wout, Woutt, 1024, 1024);
  gemm_bt<0><<<dim3(64, 24), 256, 0, stream>>>(Xbf, Wqkvt, 1024, bqkv,
                                               nullptr, nullptr, qbf, kbf, vtf, nullptr);
  attn_kernel<<<1024, 256, 0, stream>>>(qbf, kbf, vtf, X2);
  gemm_bt<1><<<dim3(64, 8), 256, 0, stream>>>(X2, Woutt, 1024, bout,
                                              e1, e2, nullptr, nullptr, nullptr, Yres);
  ln_kernel<<<8192, 256, 0, stream>>>(Yres, gamma, beta, out);
}

// Round 3
// 461.951 us; speedup vs baseline: 1.4536x; 1.1050x over previous
//
#include <hip/hip_runtime.h>
#include <stdint.h>
#include <stddef.h>

#define DIM 1024
#define HEADS 16
#define HDIM 64
#define NTOK 2048

typedef __attribute__((ext_vector_type(8))) __bf16 bf16x8;
typedef __attribute__((ext_vector_type(4))) float f32x4;
typedef __attribute__((ext_vector_type(16))) float f32x16;
typedef __attribute__((ext_vector_type(4))) short short4v;
typedef __attribute__((ext_vector_type(4))) uint32_t u32x4;

__device__ __forceinline__ short f2bs(float f) {
  // round-to-nearest-even f32 -> bf16
  uint32_t u = __builtin_bit_cast(uint32_t, f);
  uint32_t r = (u + 0x7FFFu + ((u >> 16) & 1u)) >> 16;
  return (short)r;
}

__device__ __forceinline__ uint32_t cvtpk(float lo, float hi) {
  uint32_t r;
  asm("v_cvt_pk_bf16_f32 %0, %1, %2" : "=v"(r) : "v"(lo), "v"(hi));
  return r;
}

__device__ __forceinline__ f32x4 MFMA(bf16x8 a, bf16x8 b, f32x4 c) {
  return __builtin_amdgcn_mfma_f32_16x16x32_bf16(a, b, c, 0, 0, 0);
}
__device__ __forceinline__ f32x16 MFMA32(bf16x8 a, bf16x8 b, f32x16 c) {
  return __builtin_amdgcn_mfma_f32_32x32x16_bf16(a, b, c, 0, 0, 0);
}

__device__ __forceinline__ void gl_lds16(const void* g, void* l) {
  __builtin_amdgcn_global_load_lds(
      (const __attribute__((address_space(1))) void*)g,
      (__attribute__((address_space(3))) void*)l, 16, 0, 0);
}

// ---------------- cast embeddings (f32 -> bf16 rows of X) ----------------
__global__ __launch_bounds__(256) void cast_embs(const float4* __restrict__ e1,
                                                 const float4* __restrict__ e2,
                                                 short* __restrict__ X) {
  int i = blockIdx.x * 256 + threadIdx.x;
  const int half4 = (4096 * 1024) / 4;
  float4 v = (i < half4) ? e1[i] : e2[i - half4];
  short4v o;
  o.x = f2bs(v.x); o.y = f2bs(v.y); o.z = f2bs(v.z); o.w = f2bs(v.w);
  *(short4v*)&X[(size_t)i * 4] = o;
}

// ---------------- transpose + cast weights: W[R][C] f32 -> Wt[C][R] bf16 --
__global__ __launch_bounds__(256) void transpose_cast(const float* __restrict__ W,
                                                      short* __restrict__ Wt,
                                                      int R, int C) {
  __shared__ float tile[32][33];
  int tx = threadIdx.x, ty = threadIdx.y;      // 32 x 8
  int c0 = blockIdx.x * 32, r0 = blockIdx.y * 32;
#pragma unroll
  for (int i = 0; i < 32; i += 8)
    tile[ty + i][tx] = W[(size_t)(r0 + ty + i) * C + c0 + tx];
  __syncthreads();
#pragma unroll
  for (int i = 0; i < 32; i += 8)
    Wt[(size_t)(c0 + ty + i) * R + r0 + tx] = f2bs(tile[tx][ty + i]);
}

// ---------------- MFMA GEMM, C = A[M,K] * Bt[N,K]^T ----------------------
template <int EPI>
__global__ __launch_bounds__(256, 2) void gemm_bt(
    const short* __restrict__ A, const short* __restrict__ Bt, int K,
    const float* __restrict__ bias,
    const float* __restrict__ e1, const float* __restrict__ e2,
    short* __restrict__ oq, short* __restrict__ okk, short* __restrict__ ovt,
    float* __restrict__ oy) {
  __shared__ short lA[128 * 32];
  __shared__ short lB[128 * 32];
  int tid = threadIdx.x;
  int l = tid & 63, w = tid >> 6;
  int wr = w >> 1, wc = w & 1;
  int row0 = blockIdx.x * 128, col0 = blockIdx.y * 128;
  f32x4 acc[4][4] = {};

  for (int kk = 0; kk < K; kk += 32) {
#pragma unroll
    for (int i = 0; i < 2; i++) {
      int f = i * 256 + tid;
      int r = f >> 2, cb = (f & 3) * 8;
      gl_lds16(A + (size_t)(row0 + r) * K + kk + cb, (char*)lA + (size_t)f * 16);
      gl_lds16(Bt + (size_t)(col0 + r) * K + kk + cb, (char*)lB + (size_t)f * 16);
    }
    __syncthreads();
    bf16x8 af[4], bfr[4];
#pragma unroll
    for (int mi = 0; mi < 4; mi++)
      af[mi] = *(const bf16x8*)&lA[(wr * 64 + mi * 16 + (l & 15)) * 32 + (l >> 4) * 8];
#pragma unroll
    for (int ni = 0; ni < 4; ni++)
      bfr[ni] = *(const bf16x8*)&lB[(wc * 64 + ni * 16 + (l & 15)) * 32 + (l >> 4) * 8];
#pragma unroll
    for (int mi = 0; mi < 4; mi++)
#pragma unroll
      for (int ni = 0; ni < 4; ni++)
        acc[mi][ni] = MFMA(af[mi], bfr[ni], acc[mi][ni]);
    __syncthreads();
  }

#pragma unroll
  for (int mi = 0; mi < 4; mi++) {
#pragma unroll
    for (int ni = 0; ni < 4; ni++) {
#pragma unroll
      for (int r = 0; r < 4; r++) {
        int grow = row0 + wr * 64 + mi * 16 + (l >> 4) * 4 + r;
        int gcol = col0 + wc * 64 + ni * 16 + (l & 15);
        float v = acc[mi][ni][r] + bias[gcol];
        if (EPI == 0) {
          int t = gcol >> 10, rem = gcol & 1023;
          int h = rem >> 6, d = rem & 63;
          int e = grow >> 12, b = (grow >> 11) & 1, n = grow & 2047;
          size_t ebh = (size_t)((e * 2 + b) * 16 + h) * NTOK * HDIM;
          if (t == 0) {
            // fold softmax scale * log2(e) into Q
            oq[ebh + (size_t)n * HDIM + d] = f2bs(v * 0.18033688f);
          } else if (t == 1) {
            okk[ebh + (size_t)n * HDIM + d] = f2bs(v);
          } else {
            ovt[ebh + (size_t)d * NTOK + n] = f2bs(v);
          }
        } else {
          float res = (grow < 4096) ? e1[(size_t)grow * DIM + gcol]
                                    : e2[(size_t)(grow - 4096) * DIM + gcol];
          oy[(size_t)grow * DIM + gcol] = v + res;
        }
      }
    }
  }
}

// ---------------- fused cross-attention, split-KV across waves -----------
// block = 32 q-rows; wave w owns keys [w*512, w*512+512); merge at end.
__global__ __launch_bounds__(256) void attn_kernel(
    const short* __restrict__ qbuf, const short* __restrict__ kbuf,
    const short* __restrict__ vtbuf, short* __restrict__ X2) {
  // bijective XCD swizzle: 8 instances per XCD (KV stays in that XCD's L2)
  int phys = blockIdx.x;
  int work = (phys & 7) * 512 + (phys >> 3);   // grid 4096 = 8*512
  int qb = work & 63;                          // 64 q-blocks of 32 rows
  int inst = work >> 6;                        // 0..63
  int h = inst & 15, b = (inst >> 4) & 1, a = inst >> 5;
  int tid = threadIdx.x, w = tid >> 6, l = tid & 63;
  int lo5 = l & 31, hi = l >> 5;

  size_t qo = (size_t)((a * 2 + b) * 16 + h) * NTOK * HDIM;
  size_t ko = (size_t)(((a ^ 1) * 2 + b) * 16 + h) * NTOK * HDIM;
  const short* Q = qbuf + qo;
  const short* Kp = kbuf + ko;
  const short* Vt = vtbuf + ko;
  int qrow = qb * 32 + lo5;                    // this lane's q row (= MFMA col)

  // Q B-fragments: B[col=q][k = hi*8 + 16*ks + j]  (Q pre-scaled by sc*log2e)
  bf16x8 qf[4];
#pragma unroll
  for (int ks = 0; ks < 4; ks++)
    qf[ks] = *(const bf16x8*)&Q[(size_t)qrow * HDIM + hi * 8 + ks * 16];

  f32x16 o0 = {}, o1 = {};
  float m = -1e30f, lsum = 0.f;

  const int sbeg = w * 512, send = sbeg + 512;
  for (int s0 = sbeg; s0 < send; s0 += 64) {
    // ---- fragment loads (K first, V issued behind it to overlap softmax)
    bf16x8 kf[8], vf[8];
#pragma unroll
    for (int ks = 0; ks < 4; ks++) {
      kf[2 * ks]     = *(const bf16x8*)&Kp[(size_t)(s0 + lo5) * HDIM + hi * 8 + ks * 16];
      kf[2 * ks + 1] = *(const bf16x8*)&Kp[(size_t)(s0 + 32 + lo5) * HDIM + hi * 8 + ks * 16];
    }
#pragma unroll
    for (int ks = 0; ks < 4; ks++) {
      vf[2 * ks]     = *(const bf16x8*)&Vt[(size_t)lo5 * NTOK + s0 + hi * 8 + ks * 16];
      vf[2 * ks + 1] = *(const bf16x8*)&Vt[(size_t)(32 + lo5) * NTOK + s0 + hi * 8 + ks * 16];
    }
    // ---- QK^T (swapped): st[t][reg] = S^T[kv][q = lo5]
    f32x16 st0 = {}, st1 = {};
#pragma unroll
    for (int ks = 0; ks < 4; ks++) {
      st0 = MFMA32(kf[2 * ks], qf[ks], st0);
      st1 = MFMA32(kf[2 * ks + 1], qf[ks], st1);
    }
    // ---- row max (tree) + cross-half
    float pm;
    {
      float t[16];
#pragma unroll
      for (int i = 0; i < 16; i++) t[i] = fmaxf(st0[i], st1[i]);
#pragma unroll
      for (int sd = 8; sd >= 1; sd >>= 1)
#pragma unroll
        for (int i = 0; i < sd; i++) t[i] = fmaxf(t[i], t[i + sd]);
      pm = t[0];
    }
    pm = fmaxf(pm, __shfl_xor(pm, 32));
    // ---- defer-max rescale (THR = 8 in log2 domain)
    if (!__all(pm <= m + 8.f)) {
      float mn = fmaxf(m, pm);
      float scl = exp2f(m - mn);
      lsum *= scl;
      o0 *= scl;
      o1 *= scl;
      m = mn;
    }
    // ---- P = exp2(S - m) in place, row sum (tree)
#pragma unroll
    for (int i = 0; i < 16; i++) st0[i] = exp2f(st0[i] - m);
#pragma unroll
    for (int i = 0; i < 16; i++) st1[i] = exp2f(st1[i] - m);
    float rs;
    {
      float t[16];
#pragma unroll
      for (int i = 0; i < 16; i++) t[i] = st0[i] + st1[i];
#pragma unroll
      for (int sd = 8; sd >= 1; sd >>= 1)
#pragma unroll
        for (int i = 0; i < sd; i++) t[i] += t[i + sd];
      rs = t[0];
    }
    rs += __shfl_xor(rs, 32);
    lsum += rs;
    // ---- pack P into PV B-frags via permlane32_swap (exact shfl/cndmask sub)
    bf16x8 pf[4];
#pragma unroll
    for (int ks = 0; ks < 4; ks++) {
      f32x16 pt = (ks < 2) ? st0 : st1;
      const int rb = (ks & 1) * 8;
      uint32_t A0 = cvtpk(pt[rb + 0], pt[rb + 1]);
      uint32_t A1 = cvtpk(pt[rb + 2], pt[rb + 3]);
      uint32_t B0 = cvtpk(pt[rb + 4], pt[rb + 5]);
      uint32_t B1 = cvtpk(pt[rb + 6], pt[rb + 7]);
      asm("v_permlane32_swap_b32 %0, %1" : "+v"(A0), "+v"(B0));
      asm("v_permlane32_swap_b32 %0, %1" : "+v"(A1), "+v"(B1));
      u32x4 fw;
      fw.x = A0; fw.y = A1; fw.z = B0; fw.w = B1;
      pf[ks] = __builtin_bit_cast(bf16x8, fw);
    }
    // ---- PV (O^T): C[row=d][col=q]
#pragma unroll
    for (int ks = 0; ks < 4; ks++) {
      o0 = MFMA32(vf[2 * ks], pf[ks], o0);
      o1 = MFMA32(vf[2 * ks + 1], pf[ks], o1);
    }
  }

  // ---- merge the 4 waves' online-softmax partials via LDS ----
  __shared__ float ob[4][64][36];   // [wave][lane][32 regs], stride 36 floats
  __shared__ float ml[4][2][32];    // [wave][m|l][q]
  {
    f32x4* d4 = (f32x4*)&ob[w][l][0];
    d4[0] = __builtin_shufflevector(o0, o0, 0, 1, 2, 3);
    d4[1] = __builtin_shufflevector(o0, o0, 4, 5, 6, 7);
    d4[2] = __builtin_shufflevector(o0, o0, 8, 9, 10, 11);
    d4[3] = __builtin_shufflevector(o0, o0, 12, 13, 14, 15);
    d4[4] = __builtin_shufflevector(o1, o1, 0, 1, 2, 3);
    d4[5] = __builtin_shufflevector(o1, o1, 4, 5, 6, 7);
    d4[6] = __builtin_shufflevector(o1, o1, 8, 9, 10, 11);
    d4[7] = __builtin_shufflevector(o1, o1, 12, 13, 14, 15);
    if (hi == 0) { ml[w][0][lo5] = m; ml[w][1][lo5] = lsum; }
  }
  __syncthreads();
  if (w != 0) return;

  float mm0 = ml[0][0][lo5], mm1 = ml[1][0][lo5];
  float mm2 = ml[2][0][lo5], mm3 = ml[3][0][lo5];
  float ms = fmaxf(fmaxf(mm0, mm1), fmaxf(mm2, mm3));
  float c0 = exp2f(mm0 - ms), c1 = exp2f(mm1 - ms);
  float c2 = exp2f(mm2 - ms), c3 = exp2f(mm3 - ms);
  lsum = ml[0][1][lo5] * c0 + ml[1][1][lo5] * c1 +
         ml[2][1][lo5] * c2 + ml[3][1][lo5] * c3;
#pragma unroll
  for (int i = 0; i < 16; i++) { o0[i] *= c0; o1[i] *= c0; }
#pragma unroll
  for (int w2 = 1; w2 < 4; w2++) {
    float cc = (w2 == 1) ? c1 : (w2 == 2) ? c2 : c3;
    const f32x4* s4 = (const f32x4*)&ob[w2][l][0];
#pragma unroll
    for (int g = 0; g < 4; g++) {
      f32x4 r0 = s4[g], r1 = s4[4 + g];
#pragma unroll
      for (int j = 0; j < 4; j++) {
        o0[4 * g + j] += r0[j] * cc;
        o1[4 * g + j] += r1[j] * cc;
      }
    }
  }

  // ---- epilogue: X2[token][h*64 + d] = O[q][d] / lsum, bf16
  float inv = 1.f / lsum;
  size_t obase = (size_t)(a * 4096 + b * 2048 + qrow) * DIM + h * HDIM;
#pragma unroll
  for (int g = 0; g < 4; g++) {
    short4v s4;
    s4.x = f2bs(o0[4 * g + 0] * inv);
    s4.y = f2bs(o0[4 * g + 1] * inv);
    s4.z = f2bs(o0[4 * g + 2] * inv);
    s4.w = f2bs(o0[4 * g + 3] * inv);
    *(short4v*)&X2[obase + 8 * g + 4 * hi] = s4;
    short4v s5;
    s5.x = f2bs(o1[4 * g + 0] * inv);
    s5.y = f2bs(o1[4 * g + 1] * inv);
    s5.z = f2bs(o1[4 * g + 2] * inv);
    s5.w = f2bs(o1[4 * g + 3] * inv);
    *(short4v*)&X2[obase + 32 + 8 * g + 4 * hi] = s5;
  }
}

// ---------------- LayerNorm over rows of Y (f32) -------------------------
__global__ __launch_bounds__(256) void ln_kernel(const float* __restrict__ Y,
                                                 const float* __restrict__ gamma,
                                                 const float* __restrict__ beta,
                                                 float* __restrict__ out) {
  int row = blockIdx.x, t = threadIdx.x;
  const float4 v = *(const float4*)&Y[(size_t)row * DIM + t * 4];
  float s = v.x + v.y + v.z + v.w;
  float s2 = v.x * v.x + v.y * v.y + v.z * v.z + v.w * v.w;
#pragma unroll
  for (int d = 1; d < 64; d <<= 1) { s += __shfl_xor(s, d); s2 += __shfl_xor(s2, d); }
  __shared__ float sb[8];
  int w = t >> 6, l = t & 63;
  if (l == 0) { sb[w] = s; sb[4 + w] = s2; }
  __syncthreads();
  s = sb[0] + sb[1] + sb[2] + sb[3];
  s2 = sb[4] + sb[5] + sb[6] + sb[7];
  float mu = s * (1.f / DIM);
  float var = s2 * (1.f / DIM) - mu * mu;
  float rr = rsqrtf(var + 1e-5f);
  const float4 g = *(const float4*)&gamma[t * 4];
  const float4 bb = *(const float4*)&beta[t * 4];
  float4 ov;
  ov.x = (v.x - mu) * rr * g.x + bb.x;
  ov.y = (v.y - mu) * rr * g.y + bb.y;
  ov.z = (v.z - mu) * rr * g.z + bb.z;
  ov.w = (v.w - mu) * rr * g.w + bb.w;
  *(float4*)&out[(size_t)row * DIM + t * 4] = ov;
}

extern "C" void kernel_launch(void* const* d_in, const int* in_sizes, int n_in,
                              void* d_out, int out_size, void* d_ws, size_t ws_size,
                              hipStream_t stream) {
  const float* e1 = (const float*)d_in[0];
  const float* e2 = (const float*)d_in[1];
  const float* Wqkv = (const float*)d_in[2];
  const float* bqkv = (const float*)d_in[3];
  const float* Wout = (const float*)d_in[4];
  const float* bout = (const float*)d_in[5];
  const float* gamma = (const float*)d_in[6];
  const float* beta = (const float*)d_in[7];

  char* p = (char*)d_ws;
  short* Xbf   = (short*)p;                     // 16 MiB (also X2 later)
  short* Wqkvt = (short*)(p + 16777216);        //  6 MiB
  short* Woutt = (short*)(p + 23068672);        //  2 MiB
  short* qbf   = (short*)(p + 25165824);        // 16 MiB
  short* kbf   = (short*)(p + 41943040);        // 16 MiB
  short* vtf   = (short*)(p + 58720256);        // 16 MiB
  float* Yres  = (float*)(p + 25165824);        // aliases qbf+kbf
  short* X2    = Xbf;
  float* out   = (float*)d_out;

  cast_embs<<<8192, 256, 0, stream>>>((const float4*)e1, (const float4*)e2, Xbf);
  transpose_cast<<<dim3(3072 / 32, 1024 / 32), dim3(32, 8), 0, stream>>>(Wqkv, Wqkvt, 1024, 3072);
  transpose_cast<<<dim3(1024 / 32, 1024 / 32), dim3(32, 8), 0, stream>>>(Wout, Woutt, 1024, 1024);
  gemm_bt<0><<<dim3(64, 24), 256, 0, stream>>>(Xbf, Wqkvt, 1024, bqkv,
                                               nullptr, nullptr, qbf, kbf, vtf, nullptr);
  attn_kernel<<<4096, 256, 0, stream>>>(qbf, kbf, vtf, X2);
  gemm_bt<1><<<dim3(64, 8), 256, 0, stream>>>(X2, Woutt, 1024, bout,
                                              e1, e2, nullptr, nullptr, nullptr, Yres);
  ln_kernel<<<8192, 256, 0, stream>>>(Yres, gamma, beta, out);
}

// Round 4
// 340.078 us; speedup vs baseline: 1.9745x; 1.3584x over previous
//
#include <hip/hip_runtime.h>
#include <stdint.h>
#include <stddef.h>

#define DIM 1024
#define HEADS 16
#define HDIM 64
#define NTOK 2048

typedef __attribute__((ext_vector_type(8))) __bf16 bf16x8;
typedef __attribute__((ext_vector_type(4))) float f32x4;
typedef __attribute__((ext_vector_type(16))) float f32x16;
typedef __attribute__((ext_vector_type(4))) short short4v;
typedef __attribute__((ext_vector_type(4))) uint32_t u32x4;

__device__ __forceinline__ short f2bs(float f) {
  // round-to-nearest-even f32 -> bf16
  uint32_t u = __builtin_bit_cast(uint32_t, f);
  uint32_t r = (u + 0x7FFFu + ((u >> 16) & 1u)) >> 16;
  return (short)r;
}

__device__ __forceinline__ uint32_t cvtpk(float lo, float hi) {
  uint32_t r;
  asm("v_cvt_pk_bf16_f32 %0, %1, %2" : "=v"(r) : "v"(lo), "v"(hi));
  return r;
}

__device__ __forceinline__ f32x4 MFMA(bf16x8 a, bf16x8 b, f32x4 c) {
  return __builtin_amdgcn_mfma_f32_16x16x32_bf16(a, b, c, 0, 0, 0);
}
__device__ __forceinline__ f32x16 MFMA32(bf16x8 a, bf16x8 b, f32x16 c) {
  return __builtin_amdgcn_mfma_f32_32x32x16_bf16(a, b, c, 0, 0, 0);
}

__device__ __forceinline__ void gl_lds16(const void* g, void* l) {
  __builtin_amdgcn_global_load_lds(
      (const __attribute__((address_space(1))) void*)g,
      (__attribute__((address_space(3))) void*)l, 16, 0, 0);
}

// ---------------- cast embeddings (f32 -> bf16 rows of X) ----------------
__global__ __launch_bounds__(256) void cast_embs(const float4* __restrict__ e1,
                                                 const float4* __restrict__ e2,
                                                 short* __restrict__ X) {
  int i = blockIdx.x * 256 + threadIdx.x;
  const int half4 = (4096 * 1024) / 4;
  float4 v = (i < half4) ? e1[i] : e2[i - half4];
  short4v o;
  o.x = f2bs(v.x); o.y = f2bs(v.y); o.z = f2bs(v.z); o.w = f2bs(v.w);
  *(short4v*)&X[(size_t)i * 4] = o;
}

// ---------------- transpose + cast weights: W[R][C] f32 -> Wt[C][R] bf16 --
__global__ __launch_bounds__(256) void transpose_cast(const float* __restrict__ W,
                                                      short* __restrict__ Wt,
                                                      int R, int C) {
  __shared__ float tile[32][33];
  int tx = threadIdx.x, ty = threadIdx.y;      // 32 x 8
  int c0 = blockIdx.x * 32, r0 = blockIdx.y * 32;
#pragma unroll
  for (int i = 0; i < 32; i += 8)
    tile[ty + i][tx] = W[(size_t)(r0 + ty + i) * C + c0 + tx];
  __syncthreads();
#pragma unroll
  for (int i = 0; i < 32; i += 8)
    Wt[(size_t)(c0 + ty + i) * R + r0 + tx] = f2bs(tile[tx][ty + i]);
}

// ---------------- MFMA GEMM, C = A[M,K] * Bt[N,K]^T ----------------------
// EPI 0: QKV epilogue. Q: row-major [n][d] scaled by sc*log2e.
//        K,V: packed in attn MFMA-fragment order:
//        buf[((tile*8 + frag)*64 + lane)*8 + j]  (tile=64 keys, frag=ks*2+h2)
template <int EPI>
__global__ __launch_bounds__(256, 2) void gemm_bt(
    const short* __restrict__ A, const short* __restrict__ Bt, int K,
    const float* __restrict__ bias,
    const float* __restrict__ e1, const float* __restrict__ e2,
    short* __restrict__ oq, short* __restrict__ okk, short* __restrict__ ovt,
    float* __restrict__ oy) {
  __shared__ short lA[128 * 32];
  __shared__ short lB[128 * 32];
  int tid = threadIdx.x;
  int l = tid & 63, w = tid >> 6;
  int wr = w >> 1, wc = w & 1;
  int row0 = blockIdx.x * 128, col0 = blockIdx.y * 128;
  f32x4 acc[4][4] = {};

  for (int kk = 0; kk < K; kk += 32) {
#pragma unroll
    for (int i = 0; i < 2; i++) {
      int f = i * 256 + tid;
      int r = f >> 2, cb = (f & 3) * 8;
      gl_lds16(A + (size_t)(row0 + r) * K + kk + cb, (char*)lA + (size_t)f * 16);
      gl_lds16(Bt + (size_t)(col0 + r) * K + kk + cb, (char*)lB + (size_t)f * 16);
    }
    __syncthreads();
    bf16x8 af[4], bfr[4];
#pragma unroll
    for (int mi = 0; mi < 4; mi++)
      af[mi] = *(const bf16x8*)&lA[(wr * 64 + mi * 16 + (l & 15)) * 32 + (l >> 4) * 8];
#pragma unroll
    for (int ni = 0; ni < 4; ni++)
      bfr[ni] = *(const bf16x8*)&lB[(wc * 64 + ni * 16 + (l & 15)) * 32 + (l >> 4) * 8];
#pragma unroll
    for (int mi = 0; mi < 4; mi++)
#pragma unroll
      for (int ni = 0; ni < 4; ni++)
        acc[mi][ni] = MFMA(af[mi], bfr[ni], acc[mi][ni]);
    __syncthreads();
  }

#pragma unroll
  for (int mi = 0; mi < 4; mi++) {
#pragma unroll
    for (int ni = 0; ni < 4; ni++) {
#pragma unroll
      for (int r = 0; r < 4; r++) {
        int grow = row0 + wr * 64 + mi * 16 + (l >> 4) * 4 + r;
        int gcol = col0 + wc * 64 + ni * 16 + (l & 15);
        float v = acc[mi][ni][r] + bias[gcol];
        if (EPI == 0) {
          int t = gcol >> 10, rem = gcol & 1023;
          int h = rem >> 6, d = rem & 63;
          int e = grow >> 12, b = (grow >> 11) & 1, n = grow & 2047;
          size_t ebh = (size_t)((e * 2 + b) * 16 + h) * (NTOK * HDIM);
          if (t == 0) {
            // fold softmax scale * log2(e) into Q
            oq[ebh + (size_t)n * HDIM + d] = f2bs(v * 0.18033688f);
          } else if (t == 1) {
            // K fragment pack: frag = ks*2 + h2, lane = hi*32 + lo5
            int ks = d >> 4, hi2 = (d >> 3) & 1, j = d & 7;
            int tt = n >> 6, rr = n & 63, h2 = rr >> 5, lo = rr & 31;
            okk[ebh + (((size_t)(tt * 8 + ks * 2 + h2)) * 64 + hi2 * 32 + lo) * 8 + j] = f2bs(v);
          } else {
            // V fragment pack: key decomposes to (ks,hi,j), d to (h2,lo5)
            int tt = n >> 6, rr = n & 63;
            int ks = rr >> 4, hi2 = (rr >> 3) & 1, j = rr & 7;
            int h2 = d >> 5, lo = d & 31;
            ovt[ebh + (((size_t)(tt * 8 + ks * 2 + h2)) * 64 + hi2 * 32 + lo) * 8 + j] = f2bs(v);
          }
        } else {
          float res = (grow < 4096) ? e1[(size_t)grow * DIM + gcol]
                                    : e2[(size_t)(grow - 4096) * DIM + gcol];
          oy[(size_t)grow * DIM + gcol] = v + res;
        }
      }
    }
  }
}

// ---------------- fused cross-attention: 1 wave/block, coalesced frags ---
// wave = 32 q-rows x all 2048 keys. K double-buffered 1 tile ahead.
__global__ __launch_bounds__(64, 2) void attn_kernel(
    const short* __restrict__ qbuf, const short* __restrict__ kfb,
    const short* __restrict__ vfb, short* __restrict__ X2) {
  // XCD swizzle: 8 consecutive instances per XCD (8 x 512KB = 4MB L2)
  int phys = blockIdx.x;
  int work = (phys & 7) * 512 + (phys >> 3);   // grid 4096 = 8*512
  int qb = work & 63;
  int inst = work >> 6;
  int h = inst & 15, b = (inst >> 4) & 1, a = inst >> 5;
  int l = threadIdx.x;                          // 64 = one wave
  int lo5 = l & 31, hi = l >> 5;

  size_t qo = (size_t)((a * 2 + b) * 16 + h) * (NTOK * HDIM);
  size_t ko = (size_t)(((a ^ 1) * 2 + b) * 16 + h) * (NTOK * HDIM);
  const short* Q = qbuf + qo;
  const short* Kf = kfb + ko;
  const short* Vf = vfb + ko;
  int qrow = qb * 32 + lo5;

  // Q B-fragments (pre-scaled); col=q=lo5, k = hi*8 + 16*ks + j
  bf16x8 qf[4];
#pragma unroll
  for (int ks = 0; ks < 4; ks++)
    qf[ks] = *(const bf16x8*)&Q[(size_t)qrow * HDIM + hi * 8 + ks * 16];

  const uint32_t one2 = 0x3F803F80u;  // two bf16 1.0
  u32x4 onev; onev.x = one2; onev.y = one2; onev.z = one2; onev.w = one2;
  const bf16x8 ones = __builtin_bit_cast(bf16x8, onev);

  f32x16 o0 = {}, o1 = {}, lacc = {};
  float m = -1e30f;

  bf16x8 ka[8], kb8[8], va[8];

#define LOADF(dst, buf, t)                                                   \
  {                                                                          \
    const short* _p = &buf[((size_t)(t) * 8) * 512 + l * 8];                 \
    _Pragma("unroll") for (int fi = 0; fi < 8; fi++)                         \
        dst[fi] = *(const bf16x8*)&_p[fi * 512];                             \
  }

#define STEP(kc, kn, t)                                                      \
  {                                                                          \
    LOADF(va, Vf, t);                        /* V for this step */           \
    f32x16 st0 = {}, st1 = {};                                               \
    __builtin_amdgcn_s_setprio(1);                                           \
    _Pragma("unroll") for (int ks = 0; ks < 4; ks++) {                       \
      st0 = MFMA32(kc[2 * ks], qf[ks], st0);                                 \
      st1 = MFMA32(kc[2 * ks + 1], qf[ks], st1);                             \
    }                                                                        \
    __builtin_amdgcn_s_setprio(0);                                           \
    LOADF(kn, Kf, ((t) + 1) & 31);           /* K for next step */           \
    float tt[16];                                                            \
    _Pragma("unroll") for (int i = 0; i < 16; i++)                           \
        tt[i] = fmaxf(st0[i], st1[i]);                                       \
    _Pragma("unroll") for (int sd = 8; sd >= 1; sd >>= 1)                    \
        _Pragma("unroll") for (int i = 0; i < sd; i++)                       \
            tt[i] = fmaxf(tt[i], tt[i + sd]);                                \
    float pm = fmaxf(tt[0], __shfl_xor(tt[0], 32));                          \
    if (!__all(pm <= m + 8.f)) {                                             \
      float mn = fmaxf(m, pm);                                               \
      float scl = exp2f(m - mn);                                             \
      o0 *= scl; o1 *= scl; lacc *= scl;                                     \
      m = mn;                                                                \
    }                                                                        \
    _Pragma("unroll") for (int i = 0; i < 16; i++) {                         \
      st0[i] = exp2f(st0[i] - m);                                            \
      st1[i] = exp2f(st1[i] - m);                                            \
    }                                                                        \
    bf16x8 pf[4];                                                            \
    _Pragma("unroll") for (int ks = 0; ks < 4; ks++) {                       \
      const int rb = (ks & 1) * 8;                                           \
      uint32_t A0, A1, B0, B1;                                               \
      if (ks < 2) {                                                          \
        A0 = cvtpk(st0[rb + 0], st0[rb + 1]);                                \
        A1 = cvtpk(st0[rb + 2], st0[rb + 3]);                                \
        B0 = cvtpk(st0[rb + 4], st0[rb + 5]);                                \
        B1 = cvtpk(st0[rb + 6], st0[rb + 7]);                                \
      } else {                                                               \
        A0 = cvtpk(st1[rb + 0], st1[rb + 1]);                                \
        A1 = cvtpk(st1[rb + 2], st1[rb + 3]);                                \
        B0 = cvtpk(st1[rb + 4], st1[rb + 5]);                                \
        B1 = cvtpk(st1[rb + 6], st1[rb + 7]);                                \
      }                                                                      \
      asm("v_permlane32_swap_b32 %0, %1" : "+v"(A0), "+v"(B0));              \
      asm("v_permlane32_swap_b32 %0, %1" : "+v"(A1), "+v"(B1));              \
      u32x4 fw; fw.x = A0; fw.y = A1; fw.z = B0; fw.w = B1;                  \
      pf[ks] = __builtin_bit_cast(bf16x8, fw);                               \
    }                                                                        \
    __builtin_amdgcn_s_setprio(1);                                           \
    _Pragma("unroll") for (int ks = 0; ks < 4; ks++) {                       \
      o0 = MFMA32(va[2 * ks], pf[ks], o0);                                   \
      o1 = MFMA32(va[2 * ks + 1], pf[ks], o1);                               \
      lacc = MFMA32(ones, pf[ks], lacc);     /* row-sum of P (all rows eq) */\
    }                                                                        \
    __builtin_amdgcn_s_setprio(0);                                           \
  }

  LOADF(ka, Kf, 0);
  for (int t = 0; t < 32; t += 2) {
    STEP(ka, kb8, t);
    STEP(kb8, ka, t + 1);
  }

  // ---- epilogue: X2[token][h*64 + d] = O[q][d] / lsum, bf16
  float inv = 1.f / lacc[0];
  size_t obase = (size_t)(a * 4096 + b * 2048 + qrow) * DIM + h * HDIM;
#pragma unroll
  for (int g = 0; g < 4; g++) {
    short4v s4;
    s4.x = f2bs(o0[4 * g + 0] * inv);
    s4.y = f2bs(o0[4 * g + 1] * inv);
    s4.z = f2bs(o0[4 * g + 2] * inv);
    s4.w = f2bs(o0[4 * g + 3] * inv);
    *(short4v*)&X2[obase + 8 * g + 4 * hi] = s4;
    short4v s5;
    s5.x = f2bs(o1[4 * g + 0] * inv);
    s5.y = f2bs(o1[4 * g + 1] * inv);
    s5.z = f2bs(o1[4 * g + 2] * inv);
    s5.w = f2bs(o1[4 * g + 3] * inv);
    *(short4v*)&X2[obase + 32 + 8 * g + 4 * hi] = s5;
  }
#undef LOADF
#undef STEP
}

// ---------------- LayerNorm over rows of Y (f32) -------------------------
__global__ __launch_bounds__(256) void ln_kernel(const float* __restrict__ Y,
                                                 const float* __restrict__ gamma,
                                                 const float* __restrict__ beta,
                                                 float* __restrict__ out) {
  int row = blockIdx.x, t = threadIdx.x;
  const float4 v = *(const float4*)&Y[(size_t)row * DIM + t * 4];
  float s = v.x + v.y + v.z + v.w;
  float s2 = v.x * v.x + v.y * v.y + v.z * v.z + v.w * v.w;
#pragma unroll
  for (int d = 1; d < 64; d <<= 1) { s += __shfl_xor(s, d); s2 += __shfl_xor(s2, d); }
  __shared__ float sb[8];
  int w = t >> 6, l = t & 63;
  if (l == 0) { sb[w] = s; sb[4 + w] = s2; }
  __syncthreads();
  s = sb[0] + sb[1] + sb[2] + sb[3];
  s2 = sb[4] + sb[5] + sb[6] + sb[7];
  float mu = s * (1.f / DIM);
  float var = s2 * (1.f / DIM) - mu * mu;
  float rr = rsqrtf(var + 1e-5f);
  const float4 g = *(const float4*)&gamma[t * 4];
  const float4 bb = *(const float4*)&beta[t * 4];
  float4 ov;
  ov.x = (v.x - mu) * rr * g.x + bb.x;
  ov.y = (v.y - mu) * rr * g.y + bb.y;
  ov.z = (v.z - mu) * rr * g.z + bb.z;
  ov.w = (v.w - mu) * rr * g.w + bb.w;
  *(float4*)&out[(size_t)row * DIM + t * 4] = ov;
}

extern "C" void kernel_launch(void* const* d_in, const int* in_sizes, int n_in,
                              void* d_out, int out_size, void* d_ws, size_t ws_size,
                              hipStream_t stream) {
  const float* e1 = (const float*)d_in[0];
  const float* e2 = (const float*)d_in[1];
  const float* Wqkv = (const float*)d_in[2];
  const float* bqkv = (const float*)d_in[3];
  const float* Wout = (const float*)d_in[4];
  const float* bout = (const float*)d_in[5];
  const float* gamma = (const float*)d_in[6];
  const float* beta = (const float*)d_in[7];

  char* p = (char*)d_ws;
  short* Xbf   = (short*)p;                     // 16 MiB (also X2 later)
  short* Wqkvt = (short*)(p + 16777216);        //  6 MiB
  short* Woutt = (short*)(p + 23068672);        //  2 MiB
  short* qbf   = (short*)(p + 25165824);        // 16 MiB
  short* kbf   = (short*)(p + 41943040);        // 16 MiB (fragment-packed)
  short* vtf   = (short*)(p + 58720256);        // 16 MiB (fragment-packed)
  float* Yres  = (float*)(p + 25165824);        // aliases qbf+kbf
  short* X2    = Xbf;
  float* out   = (float*)d_out;

  cast_embs<<<8192, 256, 0, stream>>>((const float4*)e1, (const float4*)e2, Xbf);
  transpose_cast<<<dim3(3072 / 32, 1024 / 32), dim3(32, 8), 0, stream>>>(Wqkv, Wqkvt, 1024, 3072);
  transpose_cast<<<dim3(1024 / 32, 1024 / 32), dim3(32, 8), 0, stream>>>(Wout, Woutt, 1024, 1024);
  gemm_bt<0><<<dim3(64, 24), 256, 0, stream>>>(Xbf, Wqkvt, 1024, bqkv,
                                               nullptr, nullptr, qbf, kbf, vtf, nullptr);
  attn_kernel<<<4096, 64, 0, stream>>>(qbf, kbf, vtf, X2);
  gemm_bt<1><<<dim3(64, 8), 256, 0, stream>>>(X2, Woutt, 1024, bout,
                                              e1, e2, nullptr, nullptr, nullptr, Yres);
  ln_kernel<<<8192, 256, 0, stream>>>(Yres, gamma, beta, out);
}